// Round 6
// baseline (465.763 us; speedup 1.0000x reference)
//
#include <hip/hip_runtime.h>

#define N_NODES 100000
#define N_EDGES 1600000
// DIN=128, DH=128, DOUT=64
#define BUCKET_SHIFT 9
#define NB 196                 // ceil(100000/512) super-buckets of 512 nodes
#define BIN_BLOCKS 782         // ceil(1600000/2048)
#define ZROW1 100000           // zero-row index in hsb (stride 128 shorts) -> byte 25.6e6
#define ZROW2 200000           // zero-row index in gsb (stride 64 shorts)  -> byte 25.6e6 (same block)

// bf16 helpers (RNE)
__device__ __forceinline__ unsigned short f2bf(float f) {
    unsigned int u = __float_as_uint(f);
    unsigned int r = (u + 0x7FFFu + ((u >> 16) & 1u)) >> 16;
    return (unsigned short)r;
}
__device__ __forceinline__ float bf2f(unsigned short b) {
    return __uint_as_float(((unsigned int)b) << 16);
}

// ---------------- zero (indeg + the 256B zero-row used by predicated gathers) ----------------
__global__ __launch_bounds__(256) void k_zero(int* __restrict__ indeg, float* __restrict__ zrow) {
    int i = blockIdx.x * 256 + threadIdx.x;
    if (i < N_NODES) indeg[i] = 0;
    if (i < 64) zrow[i] = 0.0f;
}

// ---------------- indeg histogram (int4-vectorized edge loads) ----------------
__global__ __launch_bounds__(256) void k_count(const int* __restrict__ dst, int* __restrict__ indeg) {
    int i = blockIdx.x * 256 + threadIdx.x;   // over N_EDGES/4 int4s
    if (i < N_EDGES / 4) {
        int4 d = ((const int4*)dst)[i];
        atomicAdd(&indeg[d.x], 1);
        atomicAdd(&indeg[d.y], 1);
        atomicAdd(&indeg[d.z], 1);
        atomicAdd(&indeg[d.w], 1);
    }
}

__global__ __launch_bounds__(256) void k_dinv(const int* __restrict__ indeg, float* __restrict__ dinv) {
    int i = blockIdx.x * 256 + threadIdx.x;
    if (i < N_NODES) dinv[i] = rsqrtf(1.0f + (float)indeg[i]);  // +1 = self loop
}

// ---------------- scan pass 1: 512-node tiles (tile sums == bucket counts) ----------------
__global__ __launch_bounds__(256) void k_scan1(const int* __restrict__ indeg, int* __restrict__ rowptr,
                                               int* __restrict__ bsums) {
    __shared__ int sh[256];
    int t = threadIdx.x;
    int base = blockIdx.x * 512 + t * 2;
    int v0 = (base + 0 < N_NODES) ? indeg[base + 0] : 0;
    int v1 = (base + 1 < N_NODES) ? indeg[base + 1] : 0;
    int s = v0 + v1;
    sh[t] = s;
    __syncthreads();
    for (int off = 1; off < 256; off <<= 1) {
        int u = (t >= off) ? sh[t - off] : 0;
        __syncthreads();
        sh[t] += u;
        __syncthreads();
    }
    int excl = sh[t] - s;
    if (t == 255) bsums[blockIdx.x] = sh[t];
    if (base + 0 < N_NODES) rowptr[base + 0] = excl;
    if (base + 1 < N_NODES) rowptr[base + 1] = excl + v0;
}

// ---------------- scan pass 2: exclusive scan of NB bucket counts; init bcur ----------------
__global__ __launch_bounds__(256) void k_scan2(int* __restrict__ bsums, int* __restrict__ bcur) {
    __shared__ int sh[256];
    int t = threadIdx.x;
    int v = (t < NB) ? bsums[t] : 0;
    sh[t] = v;
    __syncthreads();
    for (int off = 1; off < 256; off <<= 1) {
        int u = (t >= off) ? sh[t - off] : 0;
        __syncthreads();
        sh[t] += u;
        __syncthreads();
    }
    if (t < NB) {
        int excl = sh[t] - v;
        bsums[t] = excl;
        bcur[t] = excl;
    }
    if (t == NB - 1) bsums[NB] = sh[t];   // == N_EDGES
}

// ---------------- scan pass 3: add bucket base to rowptr ----------------
__global__ __launch_bounds__(256) void k_scan3(int* __restrict__ rowptr, const int* __restrict__ bsums) {
    int i = blockIdx.x * 256 + threadIdx.x;
    if (i < N_NODES) rowptr[i] += bsums[i >> BUCKET_SHIFT];
    if (i == 0) rowptr[N_NODES] = N_EDGES;
}

// ---------------- bin edges into bucket-ordered packed ebuf ----------------
__global__ __launch_bounds__(256) void k_bin(const int* __restrict__ src, const int* __restrict__ dst,
                                             int* __restrict__ bcur, int* __restrict__ ebuf) {
    __shared__ int hist[NB];
    __shared__ int lbase[NB];
    int t = threadIdx.x;
    int e0 = blockIdx.x * 2048 + t;
    int s[8], d[8];
#pragma unroll
    for (int j = 0; j < 8; ++j) {
        int e = e0 + j * 256;
        bool ok = e < N_EDGES;
        s[j] = ok ? src[e] : -1;
        d[j] = ok ? dst[e] : 0;
    }
    if (t < NB) hist[t] = 0;
    __syncthreads();
#pragma unroll
    for (int j = 0; j < 8; ++j)
        if (s[j] >= 0) atomicAdd(&hist[d[j] >> BUCKET_SHIFT], 1);
    __syncthreads();
    if (t < NB && hist[t] > 0) lbase[t] = atomicAdd(&bcur[t], hist[t]);
    __syncthreads();
    if (t < NB) hist[t] = 0;
    __syncthreads();
#pragma unroll
    for (int j = 0; j < 8; ++j) {
        if (s[j] >= 0) {
            int b = d[j] >> BUCKET_SHIFT;
            int r = atomicAdd(&hist[b], 1);
            ebuf[lbase[b] + r] = ((d[j] & 511) << 17) | s[j];
        }
    }
}

// ---------------- per-bucket CSR fill ----------------
__global__ __launch_bounds__(256) void k_bfill2(const int* __restrict__ ebuf, const int* __restrict__ bsums,
                                                const int* __restrict__ rowptr, int* __restrict__ csr) {
    __shared__ int cur[512];
    int b = blockIdx.x;
    int node0 = b << BUCKET_SHIFT;
    int t = threadIdx.x;
#pragma unroll
    for (int i = t; i < 512; i += 256) {
        int n = node0 + i;
        cur[i] = (n < N_NODES) ? rowptr[n] : 0;
    }
    __syncthreads();
    int s0 = bsums[b], s1 = bsums[b + 1];
    for (int i = s0 + t; i < s1; i += 256) {
        int e = ebuf[i];
        int p = atomicAdd(&cur[e >> 17], 1);
        csr[p] = e & 0x1FFFF;
    }
}

// ---------------- GEMM1: hsb = bf16((x @ W1) * dinv[row]) ----------------
__global__ __launch_bounds__(256) void k_gemm1(const float* __restrict__ x, const float* __restrict__ W1,
                                               const float* __restrict__ dinv, unsigned short* __restrict__ hsb) {
    __shared__ float Wl[128 * 128];
    __shared__ float Xl[32 * 128];
    int t = threadIdx.x;
    int row0 = blockIdx.x * 32;
    {
        const float4* W4 = (const float4*)W1;
        float4* Wl4 = (float4*)Wl;
#pragma unroll
        for (int i = 0; i < 16; ++i) Wl4[t + i * 256] = W4[t + i * 256];
        const float4* x4 = (const float4*)(x + (long long)row0 * 128);
        float4* Xl4 = (float4*)Xl;
#pragma unroll
        for (int i = 0; i < 4; ++i) Xl4[t + i * 256] = x4[t + i * 256];
    }
    __syncthreads();
    int tc = t & 31;
    int tr = t >> 5;
    float acc[4][4] = {};
    for (int k = 0; k < 128; ++k) {
        float4 w = *(const float4*)&Wl[k * 128 + tc * 4];
#pragma unroll
        for (int r = 0; r < 4; ++r) {
            float xv = Xl[(tr * 4 + r) * 128 + k];
            acc[r][0] = fmaf(xv, w.x, acc[r][0]);
            acc[r][1] = fmaf(xv, w.y, acc[r][1]);
            acc[r][2] = fmaf(xv, w.z, acc[r][2]);
            acc[r][3] = fmaf(xv, w.w, acc[r][3]);
        }
    }
#pragma unroll
    for (int r = 0; r < 4; ++r) {
        int row = row0 + tr * 4 + r;
        float s = dinv[row];
        ushort4 o;
        o.x = f2bf(acc[r][0] * s);
        o.y = f2bf(acc[r][1] * s);
        o.z = f2bf(acc[r][2] * s);
        o.w = f2bf(acc[r][3] * s);
        ((ushort4*)(hsb + (long long)row * 128))[tc] = o;
    }
}

// ---------------- aggregate layer 1 (bf16 gather, fp32 accum, predicated unroll-8) ----------------
__global__ __launch_bounds__(256) void k_agg1(const unsigned short* __restrict__ hsb, const int* __restrict__ rowptr,
                                              const int* __restrict__ csr, const float* __restrict__ dinv,
                                              const float* __restrict__ b1, float* __restrict__ h) {
    int n = (blockIdx.x * 256 + threadIdx.x) >> 6;
    int lane = threadIdx.x & 63;
    if (n >= N_NODES) return;
    ushort2 sv = ((const ushort2*)(hsb + (long long)n * 128))[lane];  // self-loop seed
    float ax = bf2f(sv.x), ay = bf2f(sv.y);
    int k = rowptr[n], end = rowptr[n + 1];
    for (; k < end; k += 8) {
        int idx[8];
#pragma unroll
        for (int j = 0; j < 8; ++j) {
            int kk = k + j;                       // wave-uniform predicate -> s_cselect
            idx[j] = (kk < end) ? csr[kk] : ZROW1;
        }
        ushort2 v[8];
#pragma unroll
        for (int j = 0; j < 8; ++j)
            v[j] = ((const ushort2*)(hsb + (long long)idx[j] * 128))[lane];
#pragma unroll
        for (int j = 0; j < 8; ++j) {
            ax += bf2f(v[j].x);
            ay += bf2f(v[j].y);
        }
    }
    float dv = dinv[n];
    float2 bb = ((const float2*)b1)[lane];
    float2 o;
    o.x = fmaxf(fmaf(dv, ax, bb.x), 0.f);
    o.y = fmaxf(fmaf(dv, ay, bb.y), 0.f);
    ((float2*)(h + (long long)n * 128))[lane] = o;
}

// ---------------- GEMM2: gsb = bf16((h @ W2) * dinv[row]) ----------------
__global__ __launch_bounds__(256) void k_gemm2(const float* __restrict__ h, const float* __restrict__ W2,
                                               const float* __restrict__ dinv, unsigned short* __restrict__ gsb) {
    __shared__ float Wl[128 * 64];
    __shared__ float Hl[32 * 132];
    int t = threadIdx.x;
    int row0 = blockIdx.x * 32;
    {
        const float4* W4 = (const float4*)W2;
        float4* Wl4 = (float4*)Wl;
#pragma unroll
        for (int i = 0; i < 8; ++i) Wl4[t + i * 256] = W4[t + i * 256];
    }
#pragma unroll
    for (int i = t; i < 1024; i += 256) {
        int r = i >> 5, c4 = i & 31;
        float4 a = ((const float4*)(h + (long long)(row0 + r) * 128))[c4];
        *(float4*)&Hl[r * 132 + c4 * 4] = a;
    }
    __syncthreads();
    int tc = t & 15;
    int tr = t >> 4;
    float acc[2][4] = {};
    for (int c = 0; c < 128; ++c) {
        float4 w = *(const float4*)&Wl[c * 64 + tc * 4];
#pragma unroll
        for (int r = 0; r < 2; ++r) {
            float hv = Hl[(tr * 2 + r) * 132 + c];
            acc[r][0] = fmaf(hv, w.x, acc[r][0]);
            acc[r][1] = fmaf(hv, w.y, acc[r][1]);
            acc[r][2] = fmaf(hv, w.z, acc[r][2]);
            acc[r][3] = fmaf(hv, w.w, acc[r][3]);
        }
    }
#pragma unroll
    for (int r = 0; r < 2; ++r) {
        int row = row0 + tr * 2 + r;
        float s = dinv[row];
        ushort4 o;
        o.x = f2bf(acc[r][0] * s);
        o.y = f2bf(acc[r][1] * s);
        o.z = f2bf(acc[r][2] * s);
        o.w = f2bf(acc[r][3] * s);
        ((ushort4*)(gsb + (long long)row * 64))[tc] = o;
    }
}

// ---------------- aggregate layer 2 (bf16 gather, fp32 accum, predicated unroll-8) ----------------
__global__ __launch_bounds__(256) void k_agg2(const unsigned short* __restrict__ gsb, const int* __restrict__ rowptr,
                                              const int* __restrict__ csr, const float* __restrict__ dinv,
                                              const float* __restrict__ b2, float* __restrict__ out) {
    int n = (blockIdx.x * 256 + threadIdx.x) >> 6;
    int lane = threadIdx.x & 63;
    if (n >= N_NODES) return;
    float acc = bf2f(gsb[(long long)n * 64 + lane]);  // self-loop seed
    int k = rowptr[n], end = rowptr[n + 1];
    for (; k < end; k += 8) {
        int idx[8];
#pragma unroll
        for (int j = 0; j < 8; ++j) {
            int kk = k + j;
            idx[j] = (kk < end) ? csr[kk] : ZROW2;
        }
        unsigned short v[8];
#pragma unroll
        for (int j = 0; j < 8; ++j)
            v[j] = gsb[(long long)idx[j] * 64 + lane];
#pragma unroll
        for (int j = 0; j < 8; ++j)
            acc += bf2f(v[j]);
    }
    out[(long long)n * 64 + lane] = fmaf(dinv[n], acc, b2[lane]);
}

extern "C" void kernel_launch(void* const* d_in, const int* in_sizes, int n_in,
                              void* d_out, int out_size, void* d_ws, size_t ws_size,
                              hipStream_t stream) {
    const float* x  = (const float*)d_in[0];
    const float* W1 = (const float*)d_in[1];
    const float* b1 = (const float*)d_in[2];
    const float* W2 = (const float*)d_in[3];
    const float* b2 = (const float*)d_in[4];
    const int*   ei = (const int*)d_in[5];
    const int* src = ei;
    const int* dst = ei + N_EDGES;
    float* out = (float*)d_out;

    char* ws = (char*)d_ws;
    int*   csr    = (int*)(ws + 0);             // 6.4 MB
    int*   indeg  = (int*)(ws + 6400000);       // 400 KB
    int*   rowptr = (int*)(ws + 6800000);       // 400 KB + 4
    float* dinv   = (float*)(ws + 7200256);     // 400 KB
    int*   bsums  = (int*)(ws + 7600256);       // (NB+1) ints
    int*   bcur   = (int*)(ws + 7604352);       // NB ints
    int*   ebuf   = (int*)(ws + 8388608);       // 6.4 MB packed (dead before gemm1)
    unsigned short* hsb = (unsigned short*)(ws + 8388608);   // 25.6 MB bf16 (aliases ebuf)
    float* zrow   = (float*)(ws + 8388608 + 25600000);       // 256 B zero-row (hsb row 100000 / gsb row 200000)
    float* h      = (float*)(ws + 59588608);    // 51.2 MB fp32
    unsigned short* gsb = hsb;                   // hsb dead after k_agg1; 12.8 MB bf16

    k_zero<<<(N_NODES + 255) / 256, 256, 0, stream>>>(indeg, zrow);
    k_count<<<(N_EDGES / 4 + 255) / 256, 256, 0, stream>>>(dst, indeg);
    k_dinv<<<(N_NODES + 255) / 256, 256, 0, stream>>>(indeg, dinv);
    k_scan1<<<NB, 256, 0, stream>>>(indeg, rowptr, bsums);
    k_scan2<<<1, 256, 0, stream>>>(bsums, bcur);
    k_scan3<<<(N_NODES + 255) / 256, 256, 0, stream>>>(rowptr, bsums);
    k_bin<<<BIN_BLOCKS, 256, 0, stream>>>(src, dst, bcur, ebuf);
    k_bfill2<<<NB, 256, 0, stream>>>(ebuf, bsums, rowptr, csr);

    k_gemm1<<<N_NODES / 32, 256, 0, stream>>>(x, W1, dinv, hsb);
    k_agg1<<<(N_NODES * 64) / 256, 256, 0, stream>>>(hsb, rowptr, csr, dinv, b1, h);
    k_gemm2<<<N_NODES / 32, 256, 0, stream>>>(h, W2, dinv, gsb);
    k_agg2<<<(N_NODES * 64) / 256, 256, 0, stream>>>(gsb, rowptr, csr, dinv, b2, out);
}

// Round 7
// 396.555 us; speedup vs baseline: 1.1745x; 1.1745x over previous
//
#include <hip/hip_runtime.h>

#define N_NODES 100000
#define N_EDGES 1600000
// DIN=128, DH=128, DOUT=64
#define BUCKET_SHIFT 9
#define NB 196                 // ceil(100000/512) super-buckets of 512 nodes
#define BIN_BLOCKS 782         // ceil(1600000/2048)
#define GEMM_BLOCKS 1563       // ceil(100000/64)

typedef short bf16x8 __attribute__((ext_vector_type(8)));
typedef float f32x4 __attribute__((ext_vector_type(4)));

// bf16 helpers (RNE)
__device__ __forceinline__ unsigned short f2bf(float f) {
    unsigned int u = __float_as_uint(f);
    unsigned int r = (u + 0x7FFFu + ((u >> 16) & 1u)) >> 16;
    return (unsigned short)r;
}
__device__ __forceinline__ float bf2f(unsigned short b) {
    return __uint_as_float(((unsigned int)b) << 16);
}

// ---------------- zero ----------------
__global__ __launch_bounds__(256) void k_zero(int* __restrict__ indeg) {
    int i = blockIdx.x * 256 + threadIdx.x;
    if (i < N_NODES) indeg[i] = 0;
}

// ---------------- indeg histogram ----------------
__global__ __launch_bounds__(256) void k_count(const int* __restrict__ dst, int* __restrict__ indeg) {
    int i = blockIdx.x * 256 + threadIdx.x;
    if (i < N_EDGES / 4) {
        int4 d = ((const int4*)dst)[i];
        atomicAdd(&indeg[d.x], 1);
        atomicAdd(&indeg[d.y], 1);
        atomicAdd(&indeg[d.z], 1);
        atomicAdd(&indeg[d.w], 1);
    }
}

// ---------------- weight transpose+cvt: w1t[c][k]=bf16(W1[k][c]), w2t[c][k]=bf16(W2[k][c]) ----------------
__global__ __launch_bounds__(256) void k_tw(const float* __restrict__ W1, const float* __restrict__ W2,
                                            unsigned short* __restrict__ w1t, unsigned short* __restrict__ w2t) {
    int t = blockIdx.x * 256 + threadIdx.x;
    if (t < 16384) {
        int k = t >> 7, c = t & 127;
        w1t[c * 128 + k] = f2bf(W1[t]);
    } else if (t < 24576) {
        int i = t - 16384;
        int k = i >> 6, c = i & 63;
        w2t[c * 128 + k] = f2bf(W2[i]);
    }
}

// ---------------- scan pass 1 (+ fused dinv): 512-node tiles ----------------
__global__ __launch_bounds__(256) void k_scan1(const int* __restrict__ indeg, int* __restrict__ rowptr,
                                               int* __restrict__ bsums, float* __restrict__ dinv) {
    __shared__ int sh[256];
    int t = threadIdx.x;
    int base = blockIdx.x * 512 + t * 2;
    int v0 = (base + 0 < N_NODES) ? indeg[base + 0] : 0;
    int v1 = (base + 1 < N_NODES) ? indeg[base + 1] : 0;
    if (base + 0 < N_NODES) dinv[base + 0] = rsqrtf(1.0f + (float)v0);
    if (base + 1 < N_NODES) dinv[base + 1] = rsqrtf(1.0f + (float)v1);
    int s = v0 + v1;
    sh[t] = s;
    __syncthreads();
    for (int off = 1; off < 256; off <<= 1) {
        int u = (t >= off) ? sh[t - off] : 0;
        __syncthreads();
        sh[t] += u;
        __syncthreads();
    }
    int excl = sh[t] - s;
    if (t == 255) bsums[blockIdx.x] = sh[t];
    if (base + 0 < N_NODES) rowptr[base + 0] = excl;
    if (base + 1 < N_NODES) rowptr[base + 1] = excl + v0;
}

// ---------------- scan pass 2 ----------------
__global__ __launch_bounds__(256) void k_scan2(int* __restrict__ bsums, int* __restrict__ bcur) {
    __shared__ int sh[256];
    int t = threadIdx.x;
    int v = (t < NB) ? bsums[t] : 0;
    sh[t] = v;
    __syncthreads();
    for (int off = 1; off < 256; off <<= 1) {
        int u = (t >= off) ? sh[t - off] : 0;
        __syncthreads();
        sh[t] += u;
        __syncthreads();
    }
    if (t < NB) {
        int excl = sh[t] - v;
        bsums[t] = excl;
        bcur[t] = excl;
    }
    if (t == NB - 1) bsums[NB] = sh[t];
}

// ---------------- scan pass 3 ----------------
__global__ __launch_bounds__(256) void k_scan3(int* __restrict__ rowptr, const int* __restrict__ bsums) {
    int i = blockIdx.x * 256 + threadIdx.x;
    if (i < N_NODES) rowptr[i] += bsums[i >> BUCKET_SHIFT];
    if (i == 0) rowptr[N_NODES] = N_EDGES;
}

// ---------------- bin edges into bucket-ordered packed ebuf ----------------
__global__ __launch_bounds__(256) void k_bin(const int* __restrict__ src, const int* __restrict__ dst,
                                             int* __restrict__ bcur, int* __restrict__ ebuf) {
    __shared__ int hist[NB];
    __shared__ int lbase[NB];
    int t = threadIdx.x;
    int e0 = blockIdx.x * 2048 + t;
    int s[8], d[8];
#pragma unroll
    for (int j = 0; j < 8; ++j) {
        int e = e0 + j * 256;
        bool ok = e < N_EDGES;
        s[j] = ok ? src[e] : -1;
        d[j] = ok ? dst[e] : 0;
    }
    if (t < NB) hist[t] = 0;
    __syncthreads();
#pragma unroll
    for (int j = 0; j < 8; ++j)
        if (s[j] >= 0) atomicAdd(&hist[d[j] >> BUCKET_SHIFT], 1);
    __syncthreads();
    if (t < NB && hist[t] > 0) lbase[t] = atomicAdd(&bcur[t], hist[t]);
    __syncthreads();
    if (t < NB) hist[t] = 0;
    __syncthreads();
#pragma unroll
    for (int j = 0; j < 8; ++j) {
        if (s[j] >= 0) {
            int b = d[j] >> BUCKET_SHIFT;
            int r = atomicAdd(&hist[b], 1);
            ebuf[lbase[b] + r] = ((d[j] & 511) << 17) | s[j];
        }
    }
}

// ---------------- per-bucket CSR fill ----------------
__global__ __launch_bounds__(256) void k_bfill2(const int* __restrict__ ebuf, const int* __restrict__ bsums,
                                                const int* __restrict__ rowptr, int* __restrict__ csr) {
    __shared__ int cur[512];
    int b = blockIdx.x;
    int node0 = b << BUCKET_SHIFT;
    int t = threadIdx.x;
#pragma unroll
    for (int i = t; i < 512; i += 256) {
        int n = node0 + i;
        cur[i] = (n < N_NODES) ? rowptr[n] : 0;
    }
    __syncthreads();
    int s0 = bsums[b], s1 = bsums[b + 1];
    for (int i = s0 + t; i < s1; i += 256) {
        int e = ebuf[i];
        int p = atomicAdd(&cur[e >> 17], 1);
        csr[p] = e & 0x1FFFF;
    }
}

// ---------------- GEMM1 (MFMA bf16): hsb = bf16((x @ W1) * dinv[row]) ----------------
// block: 64 rows x 128 cols; 4 waves, wave w handles rows w*16..+15.
// A[m=lane&15][k=quad*8+j]; B[n=lane&15][k=quad*8+j]; D col=lane&15, row=quad*4+reg.
__global__ __launch_bounds__(256) void k_gemm1(const float* __restrict__ x, const unsigned short* __restrict__ w1t,
                                               const float* __restrict__ dinv, unsigned short* __restrict__ hsb) {
    __shared__ unsigned short Xl[64 * 136];   // x tile bf16, stride 136
    __shared__ unsigned short Wl[128 * 136];  // w1t (col-major K-contig) bf16, stride 136
    int t = threadIdx.x;
    int row0 = blockIdx.x * 64;
    // stage Xl: 64x128 fp32 -> bf16
    for (int i = t; i < 64 * 32; i += 256) {  // float4 granules
        int r = i >> 5, c4 = i & 31;
        int row = row0 + r;
        float4 v = (row < N_NODES) ? ((const float4*)x)[(long long)row * 32 + c4]
                                   : make_float4(0.f, 0.f, 0.f, 0.f);
        ushort4 o;
        o.x = f2bf(v.x); o.y = f2bf(v.y); o.z = f2bf(v.z); o.w = f2bf(v.w);
        *(ushort4*)&Xl[r * 136 + c4 * 4] = o;
    }
    // stage Wl from w1t (already bf16, [col][k])
    for (int i = t; i < 128 * 16; i += 256) {  // ushort8 granules
        int r = i >> 4, c8 = i & 15;
        *(bf16x8*)&Wl[r * 136 + c8 * 8] = *(const bf16x8*)&w1t[r * 128 + c8 * 8];
    }
    __syncthreads();
    int w = t >> 6, lane = t & 63;
    int nn = lane & 15, quad = lane >> 4;
    bf16x8 a[4];
#pragma unroll
    for (int kt = 0; kt < 4; ++kt)
        a[kt] = *(const bf16x8*)&Xl[(w * 16 + nn) * 136 + kt * 32 + quad * 8];
    f32x4 acc[8];
#pragma unroll
    for (int ct = 0; ct < 8; ++ct) {
        acc[ct] = (f32x4){0.f, 0.f, 0.f, 0.f};
#pragma unroll
        for (int kt = 0; kt < 4; ++kt) {
            bf16x8 b = *(const bf16x8*)&Wl[(ct * 16 + nn) * 136 + kt * 32 + quad * 8];
            acc[ct] = __builtin_amdgcn_mfma_f32_16x16x32_bf16(a[kt], b, acc[ct], 0, 0, 0);
        }
    }
    // epilogue: scale by dinv, bf16, repack via own 16-row slice of Xl (wave-local, no barrier)
#pragma unroll
    for (int r = 0; r < 4; ++r) {
        int row = row0 + w * 16 + quad * 4 + r;
        float dv = (row < N_NODES) ? dinv[row] : 0.f;
#pragma unroll
        for (int ct = 0; ct < 8; ++ct)
            Xl[(w * 16 + quad * 4 + r) * 136 + ct * 16 + nn] = f2bf(acc[ct][r] * dv);
    }
#pragma unroll
    for (int j = 0; j < 8; ++j) {
        int c = lane + j * 64;             // 512 ushort4 chunks over 16 rows x 128 cols
        int r = c >> 5, c4 = c & 31;
        int row = row0 + w * 16 + r;
        if (row < N_NODES)
            ((ushort4*)(hsb + (long long)row * 128))[c4] = *(const ushort4*)&Xl[(w * 16 + r) * 136 + c4 * 4];
    }
}

// ---------------- aggregate layer 1 (bf16 gather, fp32 accum, unroll-4; bf16 out) ----------------
__global__ __launch_bounds__(256) void k_agg1(const unsigned short* __restrict__ hsb, const int* __restrict__ rowptr,
                                              const int* __restrict__ csr, const float* __restrict__ dinv,
                                              const float* __restrict__ b1, unsigned short* __restrict__ h) {
    int n = (blockIdx.x * 256 + threadIdx.x) >> 6;
    int lane = threadIdx.x & 63;
    if (n >= N_NODES) return;
    ushort2 sv = ((const ushort2*)(hsb + (long long)n * 128))[lane];  // self-loop seed
    float ax = bf2f(sv.x), ay = bf2f(sv.y);
    int k = rowptr[n], end = rowptr[n + 1];
    for (; k + 3 < end; k += 4) {
        int s0 = csr[k], s1 = csr[k + 1], s2 = csr[k + 2], s3 = csr[k + 3];
        ushort2 a = ((const ushort2*)(hsb + (long long)s0 * 128))[lane];
        ushort2 b = ((const ushort2*)(hsb + (long long)s1 * 128))[lane];
        ushort2 c = ((const ushort2*)(hsb + (long long)s2 * 128))[lane];
        ushort2 d = ((const ushort2*)(hsb + (long long)s3 * 128))[lane];
        ax += (bf2f(a.x) + bf2f(b.x)) + (bf2f(c.x) + bf2f(d.x));
        ay += (bf2f(a.y) + bf2f(b.y)) + (bf2f(c.y) + bf2f(d.y));
    }
    for (; k < end; ++k) {
        ushort2 a = ((const ushort2*)(hsb + (long long)csr[k] * 128))[lane];
        ax += bf2f(a.x);
        ay += bf2f(a.y);
    }
    float dv = dinv[n];
    float2 bb = ((const float2*)b1)[lane];
    ushort2 o;
    o.x = f2bf(fmaxf(fmaf(dv, ax, bb.x), 0.f));
    o.y = f2bf(fmaxf(fmaf(dv, ay, bb.y), 0.f));
    ((ushort2*)(h + (long long)n * 128))[lane] = o;
}

// ---------------- GEMM2 (MFMA bf16): gsb = bf16((h @ W2) * dinv[row]) ----------------
// block: 64 rows x 64 cols; h is already bf16.
__global__ __launch_bounds__(256) void k_gemm2(const unsigned short* __restrict__ h, const unsigned short* __restrict__ w2t,
                                               const float* __restrict__ dinv, unsigned short* __restrict__ gsb) {
    __shared__ unsigned short Hl[64 * 136];
    __shared__ unsigned short Wl[64 * 136];
    int t = threadIdx.x;
    int row0 = blockIdx.x * 64;
    for (int i = t; i < 64 * 16; i += 256) {  // ushort8 granules
        int r = i >> 4, c8 = i & 15;
        int row = row0 + r;
        bf16x8 v = (row < N_NODES) ? *(const bf16x8*)&h[(long long)row * 128 + c8 * 8]
                                   : (bf16x8){0, 0, 0, 0, 0, 0, 0, 0};
        *(bf16x8*)&Hl[r * 136 + c8 * 8] = v;
        *(bf16x8*)&Wl[r * 136 + c8 * 8] = *(const bf16x8*)&w2t[r * 128 + c8 * 8];
    }
    __syncthreads();
    int w = t >> 6, lane = t & 63;
    int nn = lane & 15, quad = lane >> 4;
    bf16x8 a[4];
#pragma unroll
    for (int kt = 0; kt < 4; ++kt)
        a[kt] = *(const bf16x8*)&Hl[(w * 16 + nn) * 136 + kt * 32 + quad * 8];
    f32x4 acc[4];
#pragma unroll
    for (int ct = 0; ct < 4; ++ct) {
        acc[ct] = (f32x4){0.f, 0.f, 0.f, 0.f};
#pragma unroll
        for (int kt = 0; kt < 4; ++kt) {
            bf16x8 b = *(const bf16x8*)&Wl[(ct * 16 + nn) * 136 + kt * 32 + quad * 8];
            acc[ct] = __builtin_amdgcn_mfma_f32_16x16x32_bf16(a[kt], b, acc[ct], 0, 0, 0);
        }
    }
#pragma unroll
    for (int r = 0; r < 4; ++r) {
        int row = row0 + w * 16 + quad * 4 + r;
        float dv = (row < N_NODES) ? dinv[row] : 0.f;
#pragma unroll
        for (int ct = 0; ct < 4; ++ct)
            Hl[(w * 16 + quad * 4 + r) * 136 + ct * 16 + nn] = f2bf(acc[ct][r] * dv);
    }
#pragma unroll
    for (int j = 0; j < 4; ++j) {
        int c = lane + j * 64;             // 256 ushort4 chunks over 16 rows x 64 cols
        int r = c >> 4, c4 = c & 15;
        int row = row0 + w * 16 + r;
        if (row < N_NODES)
            ((ushort4*)(gsb + (long long)row * 64))[c4] = *(const ushort4*)&Hl[(w * 16 + r) * 136 + c4 * 4];
    }
}

// ---------------- aggregate layer 2 (bf16 gather, fp32 accum, unroll-4) ----------------
__global__ __launch_bounds__(256) void k_agg2(const unsigned short* __restrict__ gsb, const int* __restrict__ rowptr,
                                              const int* __restrict__ csr, const float* __restrict__ dinv,
                                              const float* __restrict__ b2, float* __restrict__ out) {
    int n = (blockIdx.x * 256 + threadIdx.x) >> 6;
    int lane = threadIdx.x & 63;
    if (n >= N_NODES) return;
    float acc = bf2f(gsb[(long long)n * 64 + lane]);  // self-loop seed
    int k = rowptr[n], end = rowptr[n + 1];
    for (; k + 3 < end; k += 4) {
        int s0 = csr[k], s1 = csr[k + 1], s2 = csr[k + 2], s3 = csr[k + 3];
        float a = bf2f(gsb[(long long)s0 * 64 + lane]);
        float b = bf2f(gsb[(long long)s1 * 64 + lane]);
        float c = bf2f(gsb[(long long)s2 * 64 + lane]);
        float d = bf2f(gsb[(long long)s3 * 64 + lane]);
        acc += (a + b) + (c + d);
    }
    for (; k < end; ++k) acc += bf2f(gsb[(long long)csr[k] * 64 + lane]);
    out[(long long)n * 64 + lane] = fmaf(dinv[n], acc, b2[lane]);
}

extern "C" void kernel_launch(void* const* d_in, const int* in_sizes, int n_in,
                              void* d_out, int out_size, void* d_ws, size_t ws_size,
                              hipStream_t stream) {
    const float* x  = (const float*)d_in[0];
    const float* W1 = (const float*)d_in[1];
    const float* b1 = (const float*)d_in[2];
    const float* W2 = (const float*)d_in[3];
    const float* b2 = (const float*)d_in[4];
    const int*   ei = (const int*)d_in[5];
    const int* src = ei;
    const int* dst = ei + N_EDGES;
    float* out = (float*)d_out;

    char* ws = (char*)d_ws;
    int*   csr    = (int*)(ws + 0);             // 6.4 MB
    int*   indeg  = (int*)(ws + 6400000);       // 400 KB
    int*   rowptr = (int*)(ws + 6800000);       // 400 KB + 4
    float* dinv   = (float*)(ws + 7200256);     // 400 KB
    int*   bsums  = (int*)(ws + 7600256);       // (NB+1) ints
    int*   bcur   = (int*)(ws + 7604352);       // NB ints
    unsigned short* w1t = (unsigned short*)(ws + 7608448);  // 32 KB bf16 W1^T
    unsigned short* w2t = (unsigned short*)(ws + 7641216);  // 16 KB bf16 W2^T
    int*   ebuf   = (int*)(ws + 8388608);       // 6.4 MB packed (dead before gemm1)
    unsigned short* hsb = (unsigned short*)(ws + 8388608);  // 25.6 MB bf16 (aliases ebuf)
    unsigned short* h   = (unsigned short*)(ws + 59588608); // 25.6 MB bf16
    unsigned short* gsb = hsb;                   // hsb dead after k_agg1; 12.8 MB bf16

    k_zero<<<(N_NODES + 255) / 256, 256, 0, stream>>>(indeg);
    k_count<<<(N_EDGES / 4 + 255) / 256, 256, 0, stream>>>(dst, indeg);
    k_tw<<<96, 256, 0, stream>>>(W1, W2, w1t, w2t);
    k_scan1<<<NB, 256, 0, stream>>>(indeg, rowptr, bsums, dinv);
    k_scan2<<<1, 256, 0, stream>>>(bsums, bcur);
    k_scan3<<<(N_NODES + 255) / 256, 256, 0, stream>>>(rowptr, bsums);
    k_bin<<<BIN_BLOCKS, 256, 0, stream>>>(src, dst, bcur, ebuf);
    k_bfill2<<<NB, 256, 0, stream>>>(ebuf, bsums, rowptr, csr);

    k_gemm1<<<GEMM_BLOCKS, 256, 0, stream>>>(x, w1t, dinv, hsb);
    k_agg1<<<(N_NODES * 64) / 256, 256, 0, stream>>>(hsb, rowptr, csr, dinv, b1, h);
    k_gemm2<<<GEMM_BLOCKS, 256, 0, stream>>>(h, w2t, dinv, gsb);
    k_agg2<<<(N_NODES * 64) / 256, 256, 0, stream>>>(gsb, rowptr, csr, dinv, b2, out);
}

// Round 8
// 373.597 us; speedup vs baseline: 1.2467x; 1.0614x over previous
//
#include <hip/hip_runtime.h>

#define N_NODES 100000
#define N_EDGES 1600000
// DIN=128, DH=128, DOUT=64
#define BUCKET_SHIFT 9
#define NB 196                 // ceil(100000/512) super-buckets of 512 nodes
#define BIN_BLOCKS 782         // ceil(1600000/2048)
#define GEMM_BLOCKS 1563       // ceil(100000/64)
#define BCAP 10240             // per-bucket ebuf capacity (mean 8163, +25 sigma)

typedef short bf16x8 __attribute__((ext_vector_type(8)));
typedef float f32x4 __attribute__((ext_vector_type(4)));

// bf16 helpers (RNE)
__device__ __forceinline__ unsigned short f2bf(float f) {
    unsigned int u = __float_as_uint(f);
    unsigned int r = (u + 0x7FFFu + ((u >> 16) & 1u)) >> 16;
    return (unsigned short)r;
}
__device__ __forceinline__ float bf2f(unsigned short b) {
    return __uint_as_float(((unsigned int)b) << 16);
}

// ---------------- zero ----------------
__global__ __launch_bounds__(256) void k_zero(int* __restrict__ indeg, int* __restrict__ bcur) {
    int i = blockIdx.x * 256 + threadIdx.x;
    if (i < N_NODES) indeg[i] = 0;
    if (i < NB) bcur[i] = 0;
}

// ---------------- weight transpose+cvt ----------------
__global__ __launch_bounds__(256) void k_tw(const float* __restrict__ W1, const float* __restrict__ W2,
                                            unsigned short* __restrict__ w1t, unsigned short* __restrict__ w2t) {
    int t = blockIdx.x * 256 + threadIdx.x;
    if (t < 16384) {
        int k = t >> 7, c = t & 127;
        w1t[c * 128 + k] = f2bf(W1[t]);
    } else if (t < 24576) {
        int i = t - 16384;
        int k = i >> 6, c = i & 63;
        w2t[c * 128 + k] = f2bf(W2[i]);
    }
}

// ---------------- bin edges (fused indeg histogram; fixed-capacity bucket slabs) ----------------
__global__ __launch_bounds__(256) void k_bin(const int* __restrict__ src, const int* __restrict__ dst,
                                             int* __restrict__ bcur, int* __restrict__ ebuf,
                                             int* __restrict__ indeg) {
    __shared__ int hist[NB];
    __shared__ int lbase[NB];
    int t = threadIdx.x;
    int e0 = blockIdx.x * 2048 + t;
    int s[8], d[8];
#pragma unroll
    for (int j = 0; j < 8; ++j) {
        int e = e0 + j * 256;
        bool ok = e < N_EDGES;
        s[j] = ok ? src[e] : -1;
        d[j] = ok ? dst[e] : 0;
    }
    if (t < NB) hist[t] = 0;
    __syncthreads();
#pragma unroll
    for (int j = 0; j < 8; ++j)
        if (s[j] >= 0) {
            atomicAdd(&indeg[d[j]], 1);
            atomicAdd(&hist[d[j] >> BUCKET_SHIFT], 1);
        }
    __syncthreads();
    if (t < NB && hist[t] > 0) lbase[t] = atomicAdd(&bcur[t], hist[t]);
    __syncthreads();
    if (t < NB) hist[t] = 0;
    __syncthreads();
#pragma unroll
    for (int j = 0; j < 8; ++j) {
        if (s[j] >= 0) {
            int b = d[j] >> BUCKET_SHIFT;
            int r = lbase[b] + atomicAdd(&hist[b], 1);
            if (r < BCAP) ebuf[b * BCAP + r] = ((d[j] & 511) << 17) | s[j];
        }
    }
}

// ---------------- scan pass 1 (+ fused dinv): 512-node tiles ----------------
__global__ __launch_bounds__(256) void k_scan1(const int* __restrict__ indeg, int* __restrict__ rowptr,
                                               int* __restrict__ bsums, float* __restrict__ dinv) {
    __shared__ int sh[256];
    int t = threadIdx.x;
    int base = blockIdx.x * 512 + t * 2;
    int v0 = (base + 0 < N_NODES) ? indeg[base + 0] : 0;
    int v1 = (base + 1 < N_NODES) ? indeg[base + 1] : 0;
    if (base + 0 < N_NODES) dinv[base + 0] = rsqrtf(1.0f + (float)v0);
    if (base + 1 < N_NODES) dinv[base + 1] = rsqrtf(1.0f + (float)v1);
    int s = v0 + v1;
    sh[t] = s;
    __syncthreads();
    for (int off = 1; off < 256; off <<= 1) {
        int u = (t >= off) ? sh[t - off] : 0;
        __syncthreads();
        sh[t] += u;
        __syncthreads();
    }
    int excl = sh[t] - s;
    if (t == 255) bsums[blockIdx.x] = sh[t];
    if (base + 0 < N_NODES) rowptr[base + 0] = excl;
    if (base + 1 < N_NODES) rowptr[base + 1] = excl + v0;
}

// ---------------- scan pass 2: exclusive scan of bucket sums ----------------
__global__ __launch_bounds__(256) void k_scan2(int* __restrict__ bsums) {
    __shared__ int sh[256];
    int t = threadIdx.x;
    int v = (t < NB) ? bsums[t] : 0;
    sh[t] = v;
    __syncthreads();
    for (int off = 1; off < 256; off <<= 1) {
        int u = (t >= off) ? sh[t - off] : 0;
        __syncthreads();
        sh[t] += u;
        __syncthreads();
    }
    if (t < NB) bsums[t] = sh[t] - v;
}

// ---------------- scan pass 3 ----------------
__global__ __launch_bounds__(256) void k_scan3(int* __restrict__ rowptr, const int* __restrict__ bsums) {
    int i = blockIdx.x * 256 + threadIdx.x;
    if (i < N_NODES) rowptr[i] += bsums[i >> BUCKET_SHIFT];
    if (i == 0) rowptr[N_NODES] = N_EDGES;
}

// ---------------- per-bucket CSR fill ----------------
__global__ __launch_bounds__(256) void k_bfill2(const int* __restrict__ ebuf, const int* __restrict__ bcur,
                                                const int* __restrict__ rowptr, int* __restrict__ csr) {
    __shared__ int cur[512];
    int b = blockIdx.x;
    int node0 = b << BUCKET_SHIFT;
    int t = threadIdx.x;
#pragma unroll
    for (int i = t; i < 512; i += 256) {
        int n = node0 + i;
        cur[i] = (n < N_NODES) ? rowptr[n] : 0;
    }
    __syncthreads();
    int cnt = bcur[b];
    if (cnt > BCAP) cnt = BCAP;
    const int* eb = ebuf + b * BCAP;
    for (int i = t; i < cnt; i += 256) {
        int e = eb[i];
        int p = atomicAdd(&cur[e >> 17], 1);
        csr[p] = e & 0x1FFFF;
    }
}

// ---------------- GEMM1 (MFMA bf16): hsb = bf16((x @ W1) * dinv[row]) ----------------
__global__ __launch_bounds__(256) void k_gemm1(const float* __restrict__ x, const unsigned short* __restrict__ w1t,
                                               const float* __restrict__ dinv, unsigned short* __restrict__ hsb) {
    __shared__ unsigned short Xl[64 * 136];
    __shared__ unsigned short Wl[128 * 136];
    int t = threadIdx.x;
    int row0 = blockIdx.x * 64;
    for (int i = t; i < 64 * 32; i += 256) {
        int r = i >> 5, c4 = i & 31;
        int row = row0 + r;
        float4 v = (row < N_NODES) ? ((const float4*)x)[(long long)row * 32 + c4]
                                   : make_float4(0.f, 0.f, 0.f, 0.f);
        ushort4 o;
        o.x = f2bf(v.x); o.y = f2bf(v.y); o.z = f2bf(v.z); o.w = f2bf(v.w);
        *(ushort4*)&Xl[r * 136 + c4 * 4] = o;
    }
    for (int i = t; i < 128 * 16; i += 256) {
        int r = i >> 4, c8 = i & 15;
        *(bf16x8*)&Wl[r * 136 + c8 * 8] = *(const bf16x8*)&w1t[r * 128 + c8 * 8];
    }
    __syncthreads();
    int w = t >> 6, lane = t & 63;
    int nn = lane & 15, quad = lane >> 4;
    bf16x8 a[4];
#pragma unroll
    for (int kt = 0; kt < 4; ++kt)
        a[kt] = *(const bf16x8*)&Xl[(w * 16 + nn) * 136 + kt * 32 + quad * 8];
    f32x4 acc[8];
#pragma unroll
    for (int ct = 0; ct < 8; ++ct) {
        acc[ct] = (f32x4){0.f, 0.f, 0.f, 0.f};
#pragma unroll
        for (int kt = 0; kt < 4; ++kt) {
            bf16x8 b = *(const bf16x8*)&Wl[(ct * 16 + nn) * 136 + kt * 32 + quad * 8];
            acc[ct] = __builtin_amdgcn_mfma_f32_16x16x32_bf16(a[kt], b, acc[ct], 0, 0, 0);
        }
    }
#pragma unroll
    for (int r = 0; r < 4; ++r) {
        int row = row0 + w * 16 + quad * 4 + r;
        float dv = (row < N_NODES) ? dinv[row] : 0.f;
#pragma unroll
        for (int ct = 0; ct < 8; ++ct)
            Xl[(w * 16 + quad * 4 + r) * 136 + ct * 16 + nn] = f2bf(acc[ct][r] * dv);
    }
#pragma unroll
    for (int j = 0; j < 8; ++j) {
        int c = lane + j * 64;
        int r = c >> 5, c4 = c & 31;
        int row = row0 + w * 16 + r;
        if (row < N_NODES)
            ((ushort4*)(hsb + (long long)row * 128))[c4] = *(const ushort4*)&Xl[(w * 16 + r) * 136 + c4 * 4];
    }
}

// ---------------- aggregate layer 1: 2 rows per gather instruction ----------------
// lane half h in {0,1} covers edge k+h; each lane owns 4 cols (li*4..+3); shfl_xor(32) combines.
__global__ __launch_bounds__(256) void k_agg1(const unsigned short* __restrict__ hsb, const int* __restrict__ rowptr,
                                              const int* __restrict__ csr, const float* __restrict__ dinv,
                                              const float* __restrict__ b1, unsigned short* __restrict__ h) {
    int n = (blockIdx.x * 256 + threadIdx.x) >> 6;
    int lane = threadIdx.x & 63;
    if (n >= N_NODES) return;
    int half = lane >> 5, li = lane & 31;
    float a0, a1, a2, a3;
    {   // self-loop seed on half 0 only
        ushort4 sv = ((const ushort4*)(hsb + (long long)n * 128))[li];
        float z = half ? 0.f : 1.f;
        a0 = z * bf2f(sv.x); a1 = z * bf2f(sv.y); a2 = z * bf2f(sv.z); a3 = z * bf2f(sv.w);
    }
    int k = rowptr[n], end = rowptr[n + 1];
    for (; k + 3 < end; k += 4) {           // 4 edges: 2 dual-row gathers
        int ia = csr[k + half];
        int ib = csr[k + 2 + half];
        ushort4 va = ((const ushort4*)(hsb + (long long)ia * 128))[li];
        ushort4 vb = ((const ushort4*)(hsb + (long long)ib * 128))[li];
        a0 += bf2f(va.x) + bf2f(vb.x);
        a1 += bf2f(va.y) + bf2f(vb.y);
        a2 += bf2f(va.z) + bf2f(vb.z);
        a3 += bf2f(va.w) + bf2f(vb.w);
    }
    for (; k < end; k += 2) {               // tail, predicated per half
        int kk = k + half;
        if (kk < end) {
            int idx = csr[kk];
            ushort4 v = ((const ushort4*)(hsb + (long long)idx * 128))[li];
            a0 += bf2f(v.x); a1 += bf2f(v.y); a2 += bf2f(v.z); a3 += bf2f(v.w);
        }
    }
    a0 += __shfl_xor(a0, 32);
    a1 += __shfl_xor(a1, 32);
    a2 += __shfl_xor(a2, 32);
    a3 += __shfl_xor(a3, 32);
    if (half == 0) {
        float dv = dinv[n];
        float4 bb = ((const float4*)b1)[li];
        ushort4 o;
        o.x = f2bf(fmaxf(fmaf(dv, a0, bb.x), 0.f));
        o.y = f2bf(fmaxf(fmaf(dv, a1, bb.y), 0.f));
        o.z = f2bf(fmaxf(fmaf(dv, a2, bb.z), 0.f));
        o.w = f2bf(fmaxf(fmaf(dv, a3, bb.w), 0.f));
        ((ushort4*)(h + (long long)n * 128))[li] = o;
    }
}

// ---------------- GEMM2 (MFMA bf16): gsb = bf16((h @ W2) * dinv[row]) ----------------
__global__ __launch_bounds__(256) void k_gemm2(const unsigned short* __restrict__ h, const unsigned short* __restrict__ w2t,
                                               const float* __restrict__ dinv, unsigned short* __restrict__ gsb) {
    __shared__ unsigned short Hl[64 * 136];
    __shared__ unsigned short Wl[64 * 136];
    int t = threadIdx.x;
    int row0 = blockIdx.x * 64;
    for (int i = t; i < 64 * 16; i += 256) {
        int r = i >> 4, c8 = i & 15;
        int row = row0 + r;
        bf16x8 v = (row < N_NODES) ? *(const bf16x8*)&h[(long long)row * 128 + c8 * 8]
                                   : (bf16x8){0, 0, 0, 0, 0, 0, 0, 0};
        *(bf16x8*)&Hl[r * 136 + c8 * 8] = v;
        *(bf16x8*)&Wl[r * 136 + c8 * 8] = *(const bf16x8*)&w2t[r * 128 + c8 * 8];
    }
    __syncthreads();
    int w = t >> 6, lane = t & 63;
    int nn = lane & 15, quad = lane >> 4;
    bf16x8 a[4];
#pragma unroll
    for (int kt = 0; kt < 4; ++kt)
        a[kt] = *(const bf16x8*)&Hl[(w * 16 + nn) * 136 + kt * 32 + quad * 8];
    f32x4 acc[4];
#pragma unroll
    for (int ct = 0; ct < 4; ++ct) {
        acc[ct] = (f32x4){0.f, 0.f, 0.f, 0.f};
#pragma unroll
        for (int kt = 0; kt < 4; ++kt) {
            bf16x8 b = *(const bf16x8*)&Wl[(ct * 16 + nn) * 136 + kt * 32 + quad * 8];
            acc[ct] = __builtin_amdgcn_mfma_f32_16x16x32_bf16(a[kt], b, acc[ct], 0, 0, 0);
        }
    }
#pragma unroll
    for (int r = 0; r < 4; ++r) {
        int row = row0 + w * 16 + quad * 4 + r;
        float dv = (row < N_NODES) ? dinv[row] : 0.f;
#pragma unroll
        for (int ct = 0; ct < 4; ++ct)
            Hl[(w * 16 + quad * 4 + r) * 136 + ct * 16 + nn] = f2bf(acc[ct][r] * dv);
    }
#pragma unroll
    for (int j = 0; j < 4; ++j) {
        int c = lane + j * 64;
        int r = c >> 4, c4 = c & 15;
        int row = row0 + w * 16 + r;
        if (row < N_NODES)
            ((ushort4*)(gsb + (long long)row * 64))[c4] = *(const ushort4*)&Hl[(w * 16 + r) * 136 + c4 * 4];
    }
}

// ---------------- aggregate layer 2: 4 rows per gather instruction ----------------
// lane quarter q in {0..3} covers edge k+q; each lane owns 4 cols ((lane&15)*4..+3).
__global__ __launch_bounds__(256) void k_agg2(const unsigned short* __restrict__ gsb, const int* __restrict__ rowptr,
                                              const int* __restrict__ csr, const float* __restrict__ dinv,
                                              const float* __restrict__ b2, float* __restrict__ out) {
    int n = (blockIdx.x * 256 + threadIdx.x) >> 6;
    int lane = threadIdx.x & 63;
    if (n >= N_NODES) return;
    int q = lane >> 4, li = lane & 15;
    float a0, a1, a2, a3;
    {   // self-loop seed on quarter 0 only
        ushort4 sv = ((const ushort4*)(gsb + (long long)n * 64))[li];
        float z = (q == 0) ? 1.f : 0.f;
        a0 = z * bf2f(sv.x); a1 = z * bf2f(sv.y); a2 = z * bf2f(sv.z); a3 = z * bf2f(sv.w);
    }
    int k = rowptr[n], end = rowptr[n + 1];
    for (; k + 7 < end; k += 8) {           // 8 edges: 2 quad-row gathers
        int ia = csr[k + q];
        int ib = csr[k + 4 + q];
        ushort4 va = ((const ushort4*)(gsb + (long long)ia * 64))[li];
        ushort4 vb = ((const ushort4*)(gsb + (long long)ib * 64))[li];
        a0 += bf2f(va.x) + bf2f(vb.x);
        a1 += bf2f(va.y) + bf2f(vb.y);
        a2 += bf2f(va.z) + bf2f(vb.z);
        a3 += bf2f(va.w) + bf2f(vb.w);
    }
    for (; k < end; k += 4) {               // tail, predicated per quarter
        int kk = k + q;
        if (kk < end) {
            int idx = csr[kk];
            ushort4 v = ((const ushort4*)(gsb + (long long)idx * 64))[li];
            a0 += bf2f(v.x); a1 += bf2f(v.y); a2 += bf2f(v.z); a3 += bf2f(v.w);
        }
    }
    a0 += __shfl_xor(a0, 16); a0 += __shfl_xor(a0, 32);
    a1 += __shfl_xor(a1, 16); a1 += __shfl_xor(a1, 32);
    a2 += __shfl_xor(a2, 16); a2 += __shfl_xor(a2, 32);
    a3 += __shfl_xor(a3, 16); a3 += __shfl_xor(a3, 32);
    if (lane < 16) {
        float dv = dinv[n];
        float4 bb = ((const float4*)b2)[li];
        float4 o = make_float4(fmaf(dv, a0, bb.x), fmaf(dv, a1, bb.y),
                               fmaf(dv, a2, bb.z), fmaf(dv, a3, bb.w));
        ((float4*)(out + (long long)n * 64))[li] = o;
    }
}

extern "C" void kernel_launch(void* const* d_in, const int* in_sizes, int n_in,
                              void* d_out, int out_size, void* d_ws, size_t ws_size,
                              hipStream_t stream) {
    const float* x  = (const float*)d_in[0];
    const float* W1 = (const float*)d_in[1];
    const float* b1 = (const float*)d_in[2];
    const float* W2 = (const float*)d_in[3];
    const float* b2 = (const float*)d_in[4];
    const int*   ei = (const int*)d_in[5];
    const int* src = ei;
    const int* dst = ei + N_EDGES;
    float* out = (float*)d_out;

    char* ws = (char*)d_ws;
    int*   csr    = (int*)(ws + 0);             // 6.4 MB
    int*   indeg  = (int*)(ws + 6400000);       // 400 KB
    int*   rowptr = (int*)(ws + 6800000);       // 400 KB + 4
    float* dinv   = (float*)(ws + 7200256);     // 400 KB
    int*   bsums  = (int*)(ws + 7600256);       // NB ints
    int*   bcur   = (int*)(ws + 7604352);       // NB ints
    unsigned short* w1t = (unsigned short*)(ws + 7608448);  // 32 KB bf16 W1^T
    unsigned short* w2t = (unsigned short*)(ws + 7641216);  // 16 KB bf16 W2^T
    int*   ebuf   = (int*)(ws + 8388608);       // 196*10240*4 = 8.03 MB (dead before gemm1)
    unsigned short* hsb = (unsigned short*)(ws + 8388608);  // 25.6 MB bf16 (aliases ebuf)
    unsigned short* h   = (unsigned short*)(ws + 59588608); // 25.6 MB bf16
    unsigned short* gsb = hsb;                   // hsb dead after k_agg1; 12.8 MB bf16

    k_zero<<<(N_NODES + 255) / 256, 256, 0, stream>>>(indeg, bcur);
    k_tw<<<96, 256, 0, stream>>>(W1, W2, w1t, w2t);
    k_bin<<<BIN_BLOCKS, 256, 0, stream>>>(src, dst, bcur, ebuf, indeg);
    k_scan1<<<NB, 256, 0, stream>>>(indeg, rowptr, bsums, dinv);
    k_scan2<<<1, 256, 0, stream>>>(bsums);
    k_scan3<<<(N_NODES + 255) / 256, 256, 0, stream>>>(rowptr, bsums);
    k_bfill2<<<NB, 256, 0, stream>>>(ebuf, bcur, rowptr, csr);

    k_gemm1<<<GEMM_BLOCKS, 256, 0, stream>>>(x, w1t, dinv, hsb);
    k_agg1<<<(N_NODES * 64) / 256, 256, 0, stream>>>(hsb, rowptr, csr, dinv, b1, h);
    k_gemm2<<<GEMM_BLOCKS, 256, 0, stream>>>(h, w2t, dinv, gsb);
    k_agg2<<<(N_NODES * 64) / 256, 256, 0, stream>>>(gsb, rowptr, csr, dinv, b2, out);
}

// Round 9
// 317.176 us; speedup vs baseline: 1.4685x; 1.1779x over previous
//
#include <hip/hip_runtime.h>

#define N_NODES 100000
#define N_EDGES 1600000
// DIN=128, DH=128, DOUT=64
#define BUCKET_SHIFT 9
#define NB 196                 // ceil(100000/512) super-buckets of 512 nodes
#define BIN_BLOCKS 782         // ceil(1600000/2048)
#define GEMM_BLOCKS 1563       // ceil(100000/64)
#define BCAP 10240             // per-bucket ebuf capacity (mean 8163, +23 sigma)

typedef short bf16x8 __attribute__((ext_vector_type(8)));
typedef float f32x4 __attribute__((ext_vector_type(4)));

// bf16 helpers (RNE)
__device__ __forceinline__ unsigned short f2bf(float f) {
    unsigned int u = __float_as_uint(f);
    unsigned int r = (u + 0x7FFFu + ((u >> 16) & 1u)) >> 16;
    return (unsigned short)r;
}
__device__ __forceinline__ float bf2f(unsigned short b) {
    return __uint_as_float(((unsigned int)b) << 16);
}

// ---------------- weight transpose+cvt (+ zero bcur in spare threads) ----------------
__global__ __launch_bounds__(256) void k_tw(const float* __restrict__ W1, const float* __restrict__ W2,
                                            unsigned short* __restrict__ w1t, unsigned short* __restrict__ w2t,
                                            int* __restrict__ bcur) {
    int t = blockIdx.x * 256 + threadIdx.x;
    if (t < 16384) {
        int k = t >> 7, c = t & 127;
        w1t[c * 128 + k] = f2bf(W1[t]);
    } else if (t < 24576) {
        int i = t - 16384;
        int k = i >> 6, c = i & 63;
        w2t[c * 128 + k] = f2bf(W2[i]);
    } else if (t - 24576 < NB) {
        bcur[t - 24576] = 0;
    }
}

// ---------------- bin edges into fixed-capacity bucket slabs ----------------
__global__ __launch_bounds__(256) void k_bin(const int* __restrict__ src, const int* __restrict__ dst,
                                             int* __restrict__ bcur, int* __restrict__ ebuf) {
    __shared__ int hist[NB];
    __shared__ int lbase[NB];
    int t = threadIdx.x;
    int e0 = blockIdx.x * 2048 + t;
    int s[8], d[8];
#pragma unroll
    for (int j = 0; j < 8; ++j) {
        int e = e0 + j * 256;
        bool ok = e < N_EDGES;
        s[j] = ok ? src[e] : -1;
        d[j] = ok ? dst[e] : 0;
    }
    if (t < NB) hist[t] = 0;
    __syncthreads();
#pragma unroll
    for (int j = 0; j < 8; ++j)
        if (s[j] >= 0) atomicAdd(&hist[d[j] >> BUCKET_SHIFT], 1);
    __syncthreads();
    if (t < NB && hist[t] > 0) lbase[t] = atomicAdd(&bcur[t], hist[t]);
    __syncthreads();
    if (t < NB) hist[t] = 0;
    __syncthreads();
#pragma unroll
    for (int j = 0; j < 8; ++j) {
        if (s[j] >= 0) {
            int b = d[j] >> BUCKET_SHIFT;
            int r = lbase[b] + atomicAdd(&hist[b], 1);
            if (r < BCAP) ebuf[b * BCAP + r] = ((d[j] & 511) << 17) | s[j];
        }
    }
}

// ---------------- per-bucket: counts -> rowptr + dinv + CSR fill (one kernel) ----------------
__global__ __launch_bounds__(256) void k_bfill3(const int* __restrict__ ebuf, const int* __restrict__ bcur,
                                                int* __restrict__ rowptr, float* __restrict__ dinv,
                                                int* __restrict__ csr) {
    __shared__ int sc[256];
    __shared__ int cnt[512];
    __shared__ int cur[512];
    int b = blockIdx.x, t = threadIdx.x;
    int node0 = b << BUCKET_SHIFT;
    // bucket base: block-local exclusive scan over the 196 bucket counts
    int v = (t < NB) ? bcur[t] : 0;
    sc[t] = v;
    cnt[t] = 0;
    cnt[t + 256] = 0;
    __syncthreads();
    for (int off = 1; off < 256; off <<= 1) {
        int u = (t >= off) ? sc[t - off] : 0;
        __syncthreads();
        sc[t] += u;
        __syncthreads();
    }
    int cb = bcur[b];
    int s0 = sc[b] - cb;                 // exclusive bucket base (read before sc reuse; barrier below)
    int ctot = cb > BCAP ? BCAP : cb;
    const int* eb = ebuf + b * BCAP;
    // per-node counts from slab
    for (int i = t; i < ctot; i += 256) atomicAdd(&cnt[eb[i] >> 17], 1);
    __syncthreads();                     // also orders sc reuse after all s0 reads
    // scan 512 counts (thread t owns elements 2t, 2t+1)
    int c0 = cnt[2 * t], c1 = cnt[2 * t + 1];
    int ps = c0 + c1;
    sc[t] = ps;
    __syncthreads();
    for (int off = 1; off < 256; off <<= 1) {
        int u = (t >= off) ? sc[t - off] : 0;
        __syncthreads();
        sc[t] += u;
        __syncthreads();
    }
    int e0x = sc[t] - ps;
    int p0 = s0 + e0x, p1 = s0 + e0x + c0;
    int n0 = node0 + 2 * t, n1 = n0 + 1;
    if (n0 < N_NODES) { rowptr[n0] = p0; dinv[n0] = rsqrtf(1.0f + (float)c0); }
    if (n1 < N_NODES) { rowptr[n1] = p1; dinv[n1] = rsqrtf(1.0f + (float)c1); }
    if (b == NB - 1 && t == 0) rowptr[N_NODES] = N_EDGES;
    cur[2 * t] = p0;
    cur[2 * t + 1] = p1;
    __syncthreads();
    // fill csr
    for (int i = t; i < ctot; i += 256) {
        int e = eb[i];
        int p = atomicAdd(&cur[e >> 17], 1);
        csr[p] = e & 0x1FFFF;
    }
}

// ---------------- GEMM1 (MFMA bf16): hsb = bf16((x @ W1) * dinv[row]) ----------------
__global__ __launch_bounds__(256) void k_gemm1(const float* __restrict__ x, const unsigned short* __restrict__ w1t,
                                               const float* __restrict__ dinv, unsigned short* __restrict__ hsb) {
    __shared__ unsigned short Xl[64 * 136];
    __shared__ unsigned short Wl[128 * 136];
    int t = threadIdx.x;
    int row0 = blockIdx.x * 64;
    for (int i = t; i < 64 * 32; i += 256) {
        int r = i >> 5, c4 = i & 31;
        int row = row0 + r;
        float4 v = (row < N_NODES) ? ((const float4*)x)[(long long)row * 32 + c4]
                                   : make_float4(0.f, 0.f, 0.f, 0.f);
        ushort4 o;
        o.x = f2bf(v.x); o.y = f2bf(v.y); o.z = f2bf(v.z); o.w = f2bf(v.w);
        *(ushort4*)&Xl[r * 136 + c4 * 4] = o;
    }
    for (int i = t; i < 128 * 16; i += 256) {
        int r = i >> 4, c8 = i & 15;
        *(bf16x8*)&Wl[r * 136 + c8 * 8] = *(const bf16x8*)&w1t[r * 128 + c8 * 8];
    }
    __syncthreads();
    int w = t >> 6, lane = t & 63;
    int nn = lane & 15, quad = lane >> 4;
    bf16x8 a[4];
#pragma unroll
    for (int kt = 0; kt < 4; ++kt)
        a[kt] = *(const bf16x8*)&Xl[(w * 16 + nn) * 136 + kt * 32 + quad * 8];
    f32x4 acc[8];
#pragma unroll
    for (int ct = 0; ct < 8; ++ct) {
        acc[ct] = (f32x4){0.f, 0.f, 0.f, 0.f};
#pragma unroll
        for (int kt = 0; kt < 4; ++kt) {
            bf16x8 b = *(const bf16x8*)&Wl[(ct * 16 + nn) * 136 + kt * 32 + quad * 8];
            acc[ct] = __builtin_amdgcn_mfma_f32_16x16x32_bf16(a[kt], b, acc[ct], 0, 0, 0);
        }
    }
#pragma unroll
    for (int r = 0; r < 4; ++r) {
        int row = row0 + w * 16 + quad * 4 + r;
        float dv = (row < N_NODES) ? dinv[row] : 0.f;
#pragma unroll
        for (int ct = 0; ct < 8; ++ct)
            Xl[(w * 16 + quad * 4 + r) * 136 + ct * 16 + nn] = f2bf(acc[ct][r] * dv);
    }
#pragma unroll
    for (int j = 0; j < 8; ++j) {
        int c = lane + j * 64;
        int r = c >> 5, c4 = c & 31;
        int row = row0 + w * 16 + r;
        if (row < N_NODES)
            ((ushort4*)(hsb + (long long)row * 128))[c4] = *(const ushort4*)&Xl[(w * 16 + r) * 136 + c4 * 4];
    }
}

// ---------------- aggregate layer 1: 2 rows per gather instruction ----------------
__global__ __launch_bounds__(256) void k_agg1(const unsigned short* __restrict__ hsb, const int* __restrict__ rowptr,
                                              const int* __restrict__ csr, const float* __restrict__ dinv,
                                              const float* __restrict__ b1, unsigned short* __restrict__ h) {
    int n = (blockIdx.x * 256 + threadIdx.x) >> 6;
    int lane = threadIdx.x & 63;
    if (n >= N_NODES) return;
    int half = lane >> 5, li = lane & 31;
    float a0, a1, a2, a3;
    {   // self-loop seed on half 0 only
        ushort4 sv = ((const ushort4*)(hsb + (long long)n * 128))[li];
        float z = half ? 0.f : 1.f;
        a0 = z * bf2f(sv.x); a1 = z * bf2f(sv.y); a2 = z * bf2f(sv.z); a3 = z * bf2f(sv.w);
    }
    int k = rowptr[n], end = rowptr[n + 1];
    for (; k + 3 < end; k += 4) {
        int ia = csr[k + half];
        int ib = csr[k + 2 + half];
        ushort4 va = ((const ushort4*)(hsb + (long long)ia * 128))[li];
        ushort4 vb = ((const ushort4*)(hsb + (long long)ib * 128))[li];
        a0 += bf2f(va.x) + bf2f(vb.x);
        a1 += bf2f(va.y) + bf2f(vb.y);
        a2 += bf2f(va.z) + bf2f(vb.z);
        a3 += bf2f(va.w) + bf2f(vb.w);
    }
    for (; k < end; k += 2) {
        int kk = k + half;
        if (kk < end) {
            int idx = csr[kk];
            ushort4 v = ((const ushort4*)(hsb + (long long)idx * 128))[li];
            a0 += bf2f(v.x); a1 += bf2f(v.y); a2 += bf2f(v.z); a3 += bf2f(v.w);
        }
    }
    a0 += __shfl_xor(a0, 32);
    a1 += __shfl_xor(a1, 32);
    a2 += __shfl_xor(a2, 32);
    a3 += __shfl_xor(a3, 32);
    if (half == 0) {
        float dv = dinv[n];
        float4 bb = ((const float4*)b1)[li];
        ushort4 o;
        o.x = f2bf(fmaxf(fmaf(dv, a0, bb.x), 0.f));
        o.y = f2bf(fmaxf(fmaf(dv, a1, bb.y), 0.f));
        o.z = f2bf(fmaxf(fmaf(dv, a2, bb.z), 0.f));
        o.w = f2bf(fmaxf(fmaf(dv, a3, bb.w), 0.f));
        ((ushort4*)(h + (long long)n * 128))[li] = o;
    }
}

// ---------------- GEMM2 (MFMA bf16): gsb = bf16((h @ W2) * dinv[row]) ----------------
__global__ __launch_bounds__(256) void k_gemm2(const unsigned short* __restrict__ h, const unsigned short* __restrict__ w2t,
                                               const float* __restrict__ dinv, unsigned short* __restrict__ gsb) {
    __shared__ unsigned short Hl[64 * 136];
    __shared__ unsigned short Wl[64 * 136];
    int t = threadIdx.x;
    int row0 = blockIdx.x * 64;
    for (int i = t; i < 64 * 16; i += 256) {
        int r = i >> 4, c8 = i & 15;
        int row = row0 + r;
        bf16x8 v = (row < N_NODES) ? *(const bf16x8*)&h[(long long)row * 128 + c8 * 8]
                                   : (bf16x8){0, 0, 0, 0, 0, 0, 0, 0};
        *(bf16x8*)&Hl[r * 136 + c8 * 8] = v;
        *(bf16x8*)&Wl[r * 136 + c8 * 8] = *(const bf16x8*)&w2t[r * 128 + c8 * 8];
    }
    __syncthreads();
    int w = t >> 6, lane = t & 63;
    int nn = lane & 15, quad = lane >> 4;
    bf16x8 a[4];
#pragma unroll
    for (int kt = 0; kt < 4; ++kt)
        a[kt] = *(const bf16x8*)&Hl[(w * 16 + nn) * 136 + kt * 32 + quad * 8];
    f32x4 acc[4];
#pragma unroll
    for (int ct = 0; ct < 4; ++ct) {
        acc[ct] = (f32x4){0.f, 0.f, 0.f, 0.f};
#pragma unroll
        for (int kt = 0; kt < 4; ++kt) {
            bf16x8 b = *(const bf16x8*)&Wl[(ct * 16 + nn) * 136 + kt * 32 + quad * 8];
            acc[ct] = __builtin_amdgcn_mfma_f32_16x16x32_bf16(a[kt], b, acc[ct], 0, 0, 0);
        }
    }
#pragma unroll
    for (int r = 0; r < 4; ++r) {
        int row = row0 + w * 16 + quad * 4 + r;
        float dv = (row < N_NODES) ? dinv[row] : 0.f;
#pragma unroll
        for (int ct = 0; ct < 4; ++ct)
            Hl[(w * 16 + quad * 4 + r) * 136 + ct * 16 + nn] = f2bf(acc[ct][r] * dv);
    }
#pragma unroll
    for (int j = 0; j < 4; ++j) {
        int c = lane + j * 64;
        int r = c >> 4, c4 = c & 15;
        int row = row0 + w * 16 + r;
        if (row < N_NODES)
            ((ushort4*)(gsb + (long long)row * 64))[c4] = *(const ushort4*)&Hl[(w * 16 + r) * 136 + c4 * 4];
    }
}

// ---------------- aggregate layer 2: 4 rows per gather instruction ----------------
__global__ __launch_bounds__(256) void k_agg2(const unsigned short* __restrict__ gsb, const int* __restrict__ rowptr,
                                              const int* __restrict__ csr, const float* __restrict__ dinv,
                                              const float* __restrict__ b2, float* __restrict__ out) {
    int n = (blockIdx.x * 256 + threadIdx.x) >> 6;
    int lane = threadIdx.x & 63;
    if (n >= N_NODES) return;
    int q = lane >> 4, li = lane & 15;
    float a0, a1, a2, a3;
    {   // self-loop seed on quarter 0 only
        ushort4 sv = ((const ushort4*)(gsb + (long long)n * 64))[li];
        float z = (q == 0) ? 1.f : 0.f;
        a0 = z * bf2f(sv.x); a1 = z * bf2f(sv.y); a2 = z * bf2f(sv.z); a3 = z * bf2f(sv.w);
    }
    int k = rowptr[n], end = rowptr[n + 1];
    for (; k + 7 < end; k += 8) {
        int ia = csr[k + q];
        int ib = csr[k + 4 + q];
        ushort4 va = ((const ushort4*)(gsb + (long long)ia * 64))[li];
        ushort4 vb = ((const ushort4*)(gsb + (long long)ib * 64))[li];
        a0 += bf2f(va.x) + bf2f(vb.x);
        a1 += bf2f(va.y) + bf2f(vb.y);
        a2 += bf2f(va.z) + bf2f(vb.z);
        a3 += bf2f(va.w) + bf2f(vb.w);
    }
    for (; k < end; k += 4) {
        int kk = k + q;
        if (kk < end) {
            int idx = csr[kk];
            ushort4 v = ((const ushort4*)(gsb + (long long)idx * 64))[li];
            a0 += bf2f(v.x); a1 += bf2f(v.y); a2 += bf2f(v.z); a3 += bf2f(v.w);
        }
    }
    a0 += __shfl_xor(a0, 16); a0 += __shfl_xor(a0, 32);
    a1 += __shfl_xor(a1, 16); a1 += __shfl_xor(a1, 32);
    a2 += __shfl_xor(a2, 16); a2 += __shfl_xor(a2, 32);
    a3 += __shfl_xor(a3, 16); a3 += __shfl_xor(a3, 32);
    if (lane < 16) {
        float dv = dinv[n];
        float4 bb = ((const float4*)b2)[li];
        float4 o = make_float4(fmaf(dv, a0, bb.x), fmaf(dv, a1, bb.y),
                               fmaf(dv, a2, bb.z), fmaf(dv, a3, bb.w));
        ((float4*)(out + (long long)n * 64))[li] = o;
    }
}

extern "C" void kernel_launch(void* const* d_in, const int* in_sizes, int n_in,
                              void* d_out, int out_size, void* d_ws, size_t ws_size,
                              hipStream_t stream) {
    const float* x  = (const float*)d_in[0];
    const float* W1 = (const float*)d_in[1];
    const float* b1 = (const float*)d_in[2];
    const float* W2 = (const float*)d_in[3];
    const float* b2 = (const float*)d_in[4];
    const int*   ei = (const int*)d_in[5];
    const int* src = ei;
    const int* dst = ei + N_EDGES;
    float* out = (float*)d_out;

    char* ws = (char*)d_ws;
    int*   csr    = (int*)(ws + 0);             // 6.4 MB
    int*   rowptr = (int*)(ws + 6800000);       // 400 KB + 4
    float* dinv   = (float*)(ws + 7200256);     // 400 KB
    int*   bcur   = (int*)(ws + 7604352);       // NB ints
    unsigned short* w1t = (unsigned short*)(ws + 7608448);  // 32 KB bf16 W1^T
    unsigned short* w2t = (unsigned short*)(ws + 7641216);  // 16 KB bf16 W2^T
    int*   ebuf   = (int*)(ws + 8388608);       // 196*10240*4 = 8.03 MB (dead before gemm1)
    unsigned short* hsb = (unsigned short*)(ws + 8388608);  // 25.6 MB bf16 (aliases ebuf)
    unsigned short* h   = (unsigned short*)(ws + 59588608); // 25.6 MB bf16
    unsigned short* gsb = hsb;                   // hsb dead after k_agg1; 12.8 MB bf16

    k_tw<<<97, 256, 0, stream>>>(W1, W2, w1t, w2t, bcur);
    k_bin<<<BIN_BLOCKS, 256, 0, stream>>>(src, dst, bcur, ebuf);
    k_bfill3<<<NB, 256, 0, stream>>>(ebuf, bcur, rowptr, dinv, csr);

    k_gemm1<<<GEMM_BLOCKS, 256, 0, stream>>>(x, w1t, dinv, hsb);
    k_agg1<<<(N_NODES * 64) / 256, 256, 0, stream>>>(hsb, rowptr, csr, dinv, b1, h);
    k_gemm2<<<GEMM_BLOCKS, 256, 0, stream>>>(h, w2t, dinv, gsb);
    k_agg2<<<(N_NODES * 64) / 256, 256, 0, stream>>>(gsb, rowptr, csr, dinv, b2, out);
}